// Round 5
// baseline (19117.029 us; speedup 1.0000x reference)
//
#include <hip/hip_runtime.h>
#include <hip/hip_bf16.h>

// bigRSNN: T=8192 strictly-serial spiking RNN.
// Phase 1: 32 blocks x 576 threads. Waves 0..7 compute 32 rows (4 rows/wave,
// 16 lanes/row, 64 V-cols/lane in VGPRs). Wave 8 = sync wave.
// Exchange is PUSH-based: the last-arriving compute wave (detected via an LDS
// u64 add combiner: low32 spike bits, high32 arrival count) broadcasts the
// block's 32 spike bits wave-wide and scatter-stores a tagged 8-B flag
// {(t+1)<<16|bits_lo16, (t+1)<<16|bits_hi16} into the 31 remote consumers'
// mailboxes (mbox[slot][consumer][producer], 8 B each, 256-B sector per
// consumer). Each sync wave polls ONLY its own 4-line sector -> every flag
// line has exactly 1 reader (no read-storm arbitration against the store).
// RING=4 slots; tags are unique & monotone. One raw s_barrier per step.
// Phase 2: readout GEMM over the tagged raster + 10 IIR scans + head mean.

constexpr int T_STEPS = 8192;
constexpr int IN_DIM  = 192;
constexpr int H_DIM   = 1024;
constexpr int NBLK    = 32;
constexpr int RING    = 4;    // mailbox ring slots (skew bound 1; 4 = margin)

// ---------------------------------------------------------------- clear ws
__global__ void k_clear(unsigned int* __restrict__ p, int n) {
    int i = blockIdx.x * blockDim.x + threadIdx.x;
    if (i < n) p[i] = 0u;
}

// ---------------------------------------------------------------- phase 1
__global__ __launch_bounds__(576, 1) void k_phase1(
    const float* __restrict__ x,        // [T][192]
    const float* __restrict__ W_in,     // [H][192]
    const float* __restrict__ V,        // [H][H]
    const float* __restrict__ b_rec,    // [H]
    const float* __restrict__ alpha_h_p,
    const float* __restrict__ beta_h_p,
    unsigned long long* __restrict__ mbox,  // [RING][32 cons][32 prod] u64
    uint2* __restrict__ raster)         // [T][32] tagged words
{
    const int tid   = threadIdx.x;
    const int blk   = blockIdx.x;        // 0..31
    const int w     = tid >> 6;          // wave 0..8
    const int l     = tid & 63;
    const bool syncw = (w == 8);
    const int r_local = l >> 4;          // 0..3 (row within wave)
    const int cg      = l & 15;          // column group: cols cg*64..+63
    const int row   = (blk << 5) + (w << 2) + r_local; // compute waves only

    __shared__ unsigned int       bits_lds[2][NBLK];  // 32 spike bits per block
    __shared__ unsigned long long combine[2];         // low32 bits | count<<32

    if (tid < NBLK) { bits_lds[0][tid] = 0u; bits_lds[1][tid] = 0u; }
    if (tid == 0)   { combine[0] = 0ull; combine[1] = 0ull; }

    // ---- compute-wave register state ----
    float4 vfrag[16];
    float  wfrag[12];
    float  b_r = 0.f;
    if (!syncw) {
        const float4* vp = (const float4*)(V + (size_t)row * H_DIM + cg * 64);
        #pragma unroll
        for (int i = 0; i < 16; ++i) vfrag[i] = vp[i];
        const float* wp = W_in + row * IN_DIM + cg * 12;
        #pragma unroll
        for (int i = 0; i < 12; ++i) wfrag[i] = wp[i];
        b_r = b_rec[row];
    }
    const float ah = alpha_h_p[0];
    const float bh = beta_h_p[0];

    const float* xptr = x + cg * 12;     // 12 floats per lane, 16B-aligned
    float xr[12];
    #pragma unroll
    for (int i = 0; i < 12; ++i) xr[i] = 0.0f;   // x[-1] = 0

    float syn = 0.f, mem = 0.f, prev = 0.f;  // replicated across a row's 16 lanes

    __syncthreads();

    for (int t = 0; t < T_STEPS; ++t) {
        const int rs  = (t + 1) & 1;  // read slot: step t-1 bits
        const int wsl = t & 1;        // write slot: step t bits

        if (!syncw) {
            // prefetch x[t] (consumed next iteration)
            const float4* xp4 = (const float4*)xptr;
            float4 f0 = xp4[0], f1 = xp4[1], f2 = xp4[2];

            unsigned int b0 = bits_lds[rs][2 * cg];       // cols cg*64..+31
            unsigned int b1 = bits_lds[rs][2 * cg + 1];   // cols cg*64+32..+63

            // V @ S_{t-1} over my 64 columns (two parallel FMA chains)
            float a0 = 0.f, a1 = 0.f;
            #pragma unroll
            for (int i = 0; i < 8; ++i) {
                a0 = fmaf((float)((b0 >> (4 * i + 0)) & 1u), vfrag[i].x, a0);
                a0 = fmaf((float)((b0 >> (4 * i + 1)) & 1u), vfrag[i].y, a0);
                a0 = fmaf((float)((b0 >> (4 * i + 2)) & 1u), vfrag[i].z, a0);
                a0 = fmaf((float)((b0 >> (4 * i + 3)) & 1u), vfrag[i].w, a0);
                a1 = fmaf((float)((b1 >> (4 * i + 0)) & 1u), vfrag[8 + i].x, a1);
                a1 = fmaf((float)((b1 >> (4 * i + 1)) & 1u), vfrag[8 + i].y, a1);
                a1 = fmaf((float)((b1 >> (4 * i + 2)) & 1u), vfrag[8 + i].z, a1);
                a1 = fmaf((float)((b1 >> (4 * i + 3)) & 1u), vfrag[8 + i].w, a1);
            }
            // + W_in @ x[t-1] over my 12 k's
            #pragma unroll
            for (int i = 0; i < 12; ++i) a0 = fmaf(wfrag[i], xr[i], a0);
            float acc = a0 + a1;

            // reduce across the row's 16 lanes
            #pragma unroll
            for (int m = 1; m < 16; m <<= 1) acc += __shfl_xor(acc, m, 64);

            // state update (identical across the row's 16 lanes)
            float cur = acc + b_r;
            syn = fmaf(ah, syn, cur);
            mem = fmaf(bh, mem, syn) * (1.0f - prev);  // zero-reset, prev spike
            float spk = (mem > 1.0f) ? 1.0f : 0.0f;
            prev = spk;

            // combine: ballot -> lane0 packs 4-bit nibble -> LDS u64 add
            unsigned long long bal = __ballot(spk > 0.5f);
            unsigned int isLast = 0u, bitsAll = 0u;
            if (l == 0) {
                unsigned int nib = (unsigned int)(bal & 1ull)
                                 | ((unsigned int)((bal >> 16) & 1ull) << 1)
                                 | ((unsigned int)((bal >> 32) & 1ull) << 2)
                                 | ((unsigned int)((bal >> 48) & 1ull) << 3);
                unsigned long long add =
                    (1ull << 32) | ((unsigned long long)nib << (4 * w));
                unsigned long long old = __hip_atomic_fetch_add(&combine[wsl], add,
                        __ATOMIC_RELAXED, __HIP_MEMORY_SCOPE_WORKGROUP);
                unsigned long long nv = old + add;
                if ((nv >> 32) == 8ull) { isLast = 1u; bitsAll = (unsigned int)nv; }
            }
            // last-arriving wave pushes the tagged flag to all 31 consumers
            isLast = __shfl(isLast, 0, 64);
            if (isLast) {
                unsigned int bits = __shfl(bitsAll, 0, 64);
                unsigned int want = (unsigned int)(t + 1);
                unsigned int w0 = (want << 16) | (bits & 0xffffu);
                unsigned int w1 = (want << 16) | (bits >> 16);
                unsigned long long pack =
                    (unsigned long long)w0 | ((unsigned long long)w1 << 32);
                if (l < NBLK && l != blk) {
                    // mbox[slot][consumer=l][producer=blk]
                    __hip_atomic_store(
                        &mbox[(size_t)(((t & (RING - 1)) * NBLK + l) * NBLK + blk)],
                        pack, __ATOMIC_RELAXED, __HIP_MEMORY_SCOPE_AGENT);
                }
                if (l == 0) {
                    raster[(size_t)t * NBLK + blk] = make_uint2(w0, w1);
                    bits_lds[wsl][blk] = bits;     // own bits for t+1
                    combine[wsl] = 0ull;           // re-arm for t+2
                }
            }

            #pragma unroll
            for (int i = 0; i < 4; ++i) {
                xr[i]     = (&f0.x)[i];
                xr[4 + i] = (&f1.x)[i];
                xr[8 + i] = (&f2.x)[i];
            }
            xptr += IN_DIM;
        } else {
            // sync wave: poll OWN mailbox sector for step-t flags (tag t+1)
            if (t + 1 < T_STEPS) {
                const bool act = (l < NBLK) && (l != blk);
                const unsigned int want = (unsigned int)(t + 1);
                const unsigned long long* p =
                    &mbox[(size_t)(((t & (RING - 1)) * NBLK + blk) * NBLK + l)];
                unsigned long long vv = 0ull;
                bool ok = !act;
                if (act) {
                    vv = __hip_atomic_load(p, __ATOMIC_RELAXED,
                                           __HIP_MEMORY_SCOPE_AGENT);
                    ok = (((vv >> 16) & 0xffffull) == want) && ((vv >> 48) == want);
                }
                while (__any(!ok)) {
                    if (!ok) {
                        vv = __hip_atomic_load(p, __ATOMIC_RELAXED,
                                               __HIP_MEMORY_SCOPE_AGENT);
                        ok = (((vv >> 16) & 0xffffull) == want) && ((vv >> 48) == want);
                    }
                }
                if (act)
                    bits_lds[wsl][l] = (unsigned int)(vv & 0xffffull)
                                     | ((unsigned int)((vv >> 32) & 0xffffull) << 16);
            }
        }

        asm volatile("s_waitcnt lgkmcnt(0)" ::: "memory");
        __builtin_amdgcn_s_barrier();
        __builtin_amdgcn_sched_barrier(0);
    }
}

// ---------------------------------------------------------------- phase 2A
// R[t][rr] = W_out[rr] . S_{t-1}  (rr = h*2+o, 10 rows). W_out staged in LDS
// with pad (stride 1033) to break row-bank conflicts.
__global__ __launch_bounds__(256, 1) void k_readout_mm(
    const uint2* __restrict__ raster,  // [T][32] tagged words
    const float* __restrict__ W_out,   // [10][1024]
    float* __restrict__ R)             // [T][10]
{
    __shared__ float wlds[10 * 1033];
    for (int i = threadIdx.x; i < 10 * 1024; i += 256) {
        int r = i >> 10, c = i & 1023;
        wlds[r * 1033 + c] = W_out[i];
    }
    __syncthreads();

    int tid = threadIdx.x;
    if (tid >= 250) return;
    int tl = tid / 10, rowr = tid - tl * 10;
    int t = blockIdx.x * 25 + tl;
    if (t >= T_STEPS) return;

    float acc = 0.f;
    if (t > 0) {
        const uint2* wp = raster + (size_t)(t - 1) * NBLK;
        const float* wr = &wlds[rowr * 1033];
        for (int ww = 0; ww < NBLK; ++ww) {
            uint2 v = wp[ww];
            unsigned int bits = (v.x & 0xffffu) | ((v.y & 0xffffu) << 16);
            const float* wb = wr + ww * 32;
            #pragma unroll
            for (int j = 0; j < 32; ++j)
                acc = fmaf((float)((bits >> j) & 1u), wb[j], acc);
        }
    }
    R[t * 10 + rowr] = acc;
}

// ---------------------------------------------------------------- phase 2B
__global__ void k_scan(const float* __restrict__ R,
                       const float* __restrict__ alpha_r,
                       const float* __restrict__ beta_r,
                       float* __restrict__ memr_all)   // [T][10]
{
    int lane = threadIdx.x;
    bool act = lane < 10;
    float a = act ? alpha_r[lane >> 1] : 0.f;
    float b = act ? beta_r[lane >> 1] : 0.f;
    float syn = 0.f, mem = 0.f;
    constexpr int PF = 8;
    float buf[PF];
    #pragma unroll
    for (int i = 0; i < PF; ++i) buf[i] = act ? R[i * 10 + lane] : 0.f;

    for (int tb = 0; tb < T_STEPS; tb += PF) {
        #pragma unroll
        for (int i = 0; i < PF; ++i) {
            int t = tb + i;
            syn = fmaf(a, syn, buf[i]);
            mem = fmaf(b, mem, syn);
            if (act) memr_all[t * 10 + lane] = mem;
            int tn = t + PF;
            buf[i] = (act && tn < T_STEPS) ? R[tn * 10 + lane] : 0.f;
        }
    }
}

// ---------------------------------------------------------------- phase 2C
__global__ void k_mean(const float* __restrict__ memr_all, float* __restrict__ out) {
    int g = blockIdx.x * blockDim.x + threadIdx.x;
    if (g >= T_STEPS * 2) return;
    int t = g >> 1, o = g & 1;
    const float* m = memr_all + t * 10 + o;
    out[g] = 0.2f * (m[0] + m[2] + m[4] + m[6] + m[8]);
}

// ---------------------------------------------------------------- launch
extern "C" void kernel_launch(void* const* d_in, const int* in_sizes, int n_in,
                              void* d_out, int out_size, void* d_ws, size_t ws_size,
                              hipStream_t stream) {
    (void)in_sizes; (void)n_in; (void)out_size; (void)ws_size;
    const float* x       = (const float*)d_in[0];
    const float* W_in    = (const float*)d_in[1];
    const float* V       = (const float*)d_in[2];
    const float* b_rec   = (const float*)d_in[3];
    const float* W_out   = (const float*)d_in[4];
    const float* alpha_h = (const float*)d_in[5];
    const float* beta_h  = (const float*)d_in[6];
    const float* alpha_r = (const float*)d_in[7];
    const float* beta_r  = (const float*)d_in[8];
    float* out = (float*)d_out;

    char* wsb = (char*)d_ws;
    unsigned long long* mbox = (unsigned long long*)wsb;   // 4*32*32*8 = 32 KB
    uint2* raster  = (uint2*)(wsb + RING * NBLK * NBLK * 8);          // 2 MB
    float* Rbuf    = (float*)(wsb + RING * NBLK * NBLK * 8
                              + (size_t)T_STEPS * NBLK * 8);          // 320 KB
    float* memr_all = Rbuf + (size_t)T_STEPS * 10;                    // 320 KB

    int nclr = RING * NBLK * NBLK * 2;   // mailbox region in u32s
    k_clear<<<(nclr + 255) / 256, 256, 0, stream>>>((unsigned int*)mbox, nclr);
    k_phase1<<<NBLK, 576, 0, stream>>>(x, W_in, V, b_rec, alpha_h, beta_h,
                                       mbox, raster);
    k_readout_mm<<<(T_STEPS + 24) / 25, 256, 0, stream>>>(raster, W_out, Rbuf);
    k_scan<<<1, 64, 0, stream>>>(Rbuf, alpha_r, beta_r, memr_all);
    k_mean<<<(T_STEPS * 2 + 255) / 256, 256, 0, stream>>>(memr_all, out);
}

// Round 6
// 17781.061 us; speedup vs baseline: 1.0751x; 1.0751x over previous
//
#include <hip/hip_runtime.h>
#include <hip/hip_bf16.h>

// bigRSNN: T=8192 strictly-serial spiking RNN.
// Phase 1: 32 blocks x 576 threads, BARRIER-FREE step loop.
//   Waves 0..7 compute 32 rows (4 rows/wave, 16 lanes/row, 64 V-cols/lane in
//   VGPRs). Wave 8 = sync wave, free-running: polls its own push-mailbox
//   sector for step-t flags, writes remote bits into an LDS ring slot, then
//   release-bumps rdySync. Compute waves acquire-spin on {rdySync,rdyOwn}
//   (one broadcast ds_read_b64), compute, combine via LDS u64 atomic add;
//   the last-arriving wave scatter-stores the tagged 8-B flag to the 31
//   remote mailboxes, writes own bits + raster, release-bumps rdyOwn.
//   Ring reuse safety: global mailbox dependency bounds intra/inter-block
//   skew to <2 steps < RING=4. All spin loops carry independent FMA burn
//   chains (hidden under memory latency) to keep VALU issue activity up so
//   DVFS holds high clocks.
// Phase 2: readout GEMM over the tagged raster + 10 IIR scans + head mean.

constexpr int T_STEPS = 8192;
constexpr int IN_DIM  = 192;
constexpr int H_DIM   = 1024;
constexpr int NBLK    = 32;
constexpr int RING    = 4;

// ---------------------------------------------------------------- clear ws
__global__ void k_clear(unsigned int* __restrict__ p, int n) {
    int i = blockIdx.x * blockDim.x + threadIdx.x;
    if (i < n) p[i] = 0u;
}

// ---------------------------------------------------------------- phase 1
__global__ __launch_bounds__(576, 1) void k_phase1(
    const float* __restrict__ x,        // [T][192]
    const float* __restrict__ W_in,     // [H][192]
    const float* __restrict__ V,        // [H][H]
    const float* __restrict__ b_rec,    // [H]
    const float* __restrict__ alpha_h_p,
    const float* __restrict__ beta_h_p,
    unsigned long long* __restrict__ mbox,  // [RING][32 cons][32 prod] u64
    uint2* __restrict__ raster)         // [T][32] tagged words
{
    const int tid   = threadIdx.x;
    const int blk   = blockIdx.x;        // 0..31
    const int w     = tid >> 6;          // wave 0..8
    const int l     = tid & 63;
    const bool syncw = (w == 8);
    const int r_local = l >> 4;          // 0..3 (row within wave)
    const int cg      = l & 15;          // column group: cols cg*64..+63
    const int row   = (blk << 5) + (w << 2) + r_local; // compute waves only

    __shared__ unsigned int       bits_lds[RING][NBLK]; // slot = step&3
    __shared__ unsigned long long combine[2];           // low32 bits|count<<32
    __shared__ unsigned long long rdyPack;              // lo=rdySync, hi=rdyOwn

    for (int i = tid; i < RING * NBLK; i += 576)
        ((unsigned int*)bits_lds)[i] = 0u;
    if (tid == 0) { combine[0] = 0ull; combine[1] = 0ull; rdyPack = 0ull; }

    unsigned int* rp = (unsigned int*)&rdyPack;   // rp[0]=sync, rp[1]=own

    // ---- compute-wave register state ----
    float4 vfrag[16];
    float  wfrag[12];
    float  b_r = 0.f;
    if (!syncw) {
        const float4* vp = (const float4*)(V + (size_t)row * H_DIM + cg * 64);
        #pragma unroll
        for (int i = 0; i < 16; ++i) vfrag[i] = vp[i];
        const float* wp = W_in + row * IN_DIM + cg * 12;
        #pragma unroll
        for (int i = 0; i < 12; ++i) wfrag[i] = wp[i];
        b_r = b_rec[row];
    }
    const float ah = alpha_h_p[0];
    const float bh = beta_h_p[0];

    __syncthreads();   // init visible to all waves (once, outside the loop)

    // burn-chain registers (escape via asm sink so they can't be DCE'd)
    float u0 = 1.02f, u1 = 1.03f, u2 = 1.05f, u3 = 1.07f;
    const float bc = 1.0000001f, bd = 1e-30f;

    if (syncw) {
        // ------------- sync wave: free-running mailbox -> LDS pump -------------
        const bool act = (l < NBLK) && (l != blk);
        for (int t = 0; t < T_STEPS - 1; ++t) {
            const unsigned int want = (unsigned int)(t + 1);
            const unsigned long long good =
                ((unsigned long long)want << 16) | ((unsigned long long)want << 48);
            const unsigned long long* p =
                &mbox[(size_t)(((t & (RING - 1)) * NBLK + blk) * NBLK + l)];
            unsigned long long vv = act
                ? __hip_atomic_load(p, __ATOMIC_RELAXED, __HIP_MEMORY_SCOPE_AGENT)
                : good;
            bool ok = (((vv >> 16) & 0xffffull) == want) && ((vv >> 48) == want);
            while (__any(!ok)) {
                if (!ok)
                    vv = __hip_atomic_load(p, __ATOMIC_RELAXED,
                                           __HIP_MEMORY_SCOPE_AGENT);
                #pragma unroll
                for (int i = 0; i < 8; ++i) {   // burn under load latency
                    u0 = fmaf(u0, bc, bd); u1 = fmaf(u1, bc, bd);
                    u2 = fmaf(u2, bc, bd); u3 = fmaf(u3, bc, bd);
                }
                ok = (((vv >> 16) & 0xffffull) == want) && ((vv >> 48) == want);
            }
            if (act)
                bits_lds[t & (RING - 1)][l] =
                    (unsigned int)(vv & 0xffffull)
                    | ((unsigned int)((vv >> 32) & 0xffffull) << 16);
            if (l == 0)
                __hip_atomic_store(&rp[0], (unsigned int)(t + 1),
                                   __ATOMIC_RELEASE, __HIP_MEMORY_SCOPE_WORKGROUP);
        }
    } else {
        // ------------- compute waves -------------
        const float* xptr = x + cg * 12;
        float xr[12];
        #pragma unroll
        for (int i = 0; i < 12; ++i) xr[i] = 0.0f;   // x[-1] = 0
        float syn = 0.f, mem = 0.f, prev = 0.f;

        for (int t = 0; t < T_STEPS; ++t) {
            // issue x[t] prefetch (consumed next step); overlaps the spin
            const float4* xp4 = (const float4*)xptr;
            float4 f0 = xp4[0], f1 = xp4[1], f2 = xp4[2];

            // acquire-spin: remote bits (rdySync>=t) and own bits (rdyOwn>=t)
            unsigned long long rv = __hip_atomic_load(&rdyPack, __ATOMIC_ACQUIRE,
                                        __HIP_MEMORY_SCOPE_WORKGROUP);
            while ((unsigned int)rv < (unsigned int)t ||
                   (unsigned int)(rv >> 32) < (unsigned int)t) {
                #pragma unroll
                for (int i = 0; i < 4; ++i) {   // burn under LDS latency
                    u0 = fmaf(u0, bc, bd); u1 = fmaf(u1, bc, bd);
                    u2 = fmaf(u2, bc, bd); u3 = fmaf(u3, bc, bd);
                }
                rv = __hip_atomic_load(&rdyPack, __ATOMIC_ACQUIRE,
                                       __HIP_MEMORY_SCOPE_WORKGROUP);
            }

            const int slot = (t + RING - 1) & (RING - 1);   // (t-1) & 3
            unsigned int b0 = bits_lds[slot][2 * cg];       // cols cg*64..+31
            unsigned int b1 = bits_lds[slot][2 * cg + 1];   // cols +32..+63

            // V @ S_{t-1} over my 64 columns (two parallel FMA chains)
            float a0 = 0.f, a1 = 0.f;
            #pragma unroll
            for (int i = 0; i < 8; ++i) {
                a0 = fmaf((float)((b0 >> (4 * i + 0)) & 1u), vfrag[i].x, a0);
                a0 = fmaf((float)((b0 >> (4 * i + 1)) & 1u), vfrag[i].y, a0);
                a0 = fmaf((float)((b0 >> (4 * i + 2)) & 1u), vfrag[i].z, a0);
                a0 = fmaf((float)((b0 >> (4 * i + 3)) & 1u), vfrag[i].w, a0);
                a1 = fmaf((float)((b1 >> (4 * i + 0)) & 1u), vfrag[8 + i].x, a1);
                a1 = fmaf((float)((b1 >> (4 * i + 1)) & 1u), vfrag[8 + i].y, a1);
                a1 = fmaf((float)((b1 >> (4 * i + 2)) & 1u), vfrag[8 + i].z, a1);
                a1 = fmaf((float)((b1 >> (4 * i + 3)) & 1u), vfrag[8 + i].w, a1);
            }
            // + W_in @ x[t-1] over my 12 k's
            #pragma unroll
            for (int i = 0; i < 12; ++i) a0 = fmaf(wfrag[i], xr[i], a0);
            float acc = a0 + a1;

            // reduce across the row's 16 lanes
            #pragma unroll
            for (int m = 1; m < 16; m <<= 1) acc += __shfl_xor(acc, m, 64);

            // state update (identical across the row's 16 lanes)
            float cur = acc + b_r;
            syn = fmaf(ah, syn, cur);
            mem = fmaf(bh, mem, syn) * (1.0f - prev);   // zero-reset, prev spike
            float spk = (mem > 1.0f) ? 1.0f : 0.0f;
            prev = spk;

            // combine: ballot -> lane0 packs 4-bit nibble -> LDS u64 add
            unsigned long long bal = __ballot(spk > 0.5f);
            unsigned int isLast = 0u, bitsAll = 0u;
            if (l == 0) {
                unsigned int nib = (unsigned int)(bal & 1ull)
                                 | ((unsigned int)((bal >> 16) & 1ull) << 1)
                                 | ((unsigned int)((bal >> 32) & 1ull) << 2)
                                 | ((unsigned int)((bal >> 48) & 1ull) << 3);
                unsigned long long add =
                    (1ull << 32) | ((unsigned long long)nib << (4 * w));
                unsigned long long old = __hip_atomic_fetch_add(&combine[t & 1],
                        add, __ATOMIC_RELAXED, __HIP_MEMORY_SCOPE_WORKGROUP);
                unsigned long long nv = old + add;
                if ((nv >> 32) == 8ull) { isLast = 1u; bitsAll = (unsigned int)nv; }
            }
            isLast = __shfl(isLast, 0, 64);
            if (isLast) {
                unsigned int bits = __shfl(bitsAll, 0, 64);
                unsigned int want = (unsigned int)(t + 1);
                unsigned int w0t = (want << 16) | (bits & 0xffffu);
                unsigned int w1t = (want << 16) | (bits >> 16);
                unsigned long long pack =
                    (unsigned long long)w0t | ((unsigned long long)w1t << 32);
                if (l < NBLK && l != blk) {
                    // push to mbox[slot][consumer=l][producer=blk]
                    __hip_atomic_store(
                        &mbox[(size_t)(((t & (RING - 1)) * NBLK + l) * NBLK + blk)],
                        pack, __ATOMIC_RELAXED, __HIP_MEMORY_SCOPE_AGENT);
                }
                if (l == 0) {
                    raster[(size_t)t * NBLK + blk] = make_uint2(w0t, w1t);
                    bits_lds[t & (RING - 1)][blk] = bits;   // own bits
                    combine[t & 1] = 0ull;                  // re-arm for t+2
                    __hip_atomic_store(&rp[1], (unsigned int)(t + 1),
                                       __ATOMIC_RELEASE,
                                       __HIP_MEMORY_SCOPE_WORKGROUP);
                }
            }

            #pragma unroll
            for (int i = 0; i < 4; ++i) {
                xr[i]     = (&f0.x)[i];
                xr[4 + i] = (&f1.x)[i];
                xr[8 + i] = (&f2.x)[i];
            }
            xptr += IN_DIM;
        }
    }
    // keep burn chains alive (prevents DCE; negligible cost)
    asm volatile("" :: "v"(u0), "v"(u1), "v"(u2), "v"(u3));
}

// ---------------------------------------------------------------- phase 2A
// R[t][rr] = W_out[rr] . S_{t-1}  (rr = h*2+o, 10 rows). W_out staged in LDS
// with pad (stride 1033) to break row-bank conflicts.
__global__ __launch_bounds__(256, 1) void k_readout_mm(
    const uint2* __restrict__ raster,  // [T][32] tagged words
    const float* __restrict__ W_out,   // [10][1024]
    float* __restrict__ R)             // [T][10]
{
    __shared__ float wlds[10 * 1033];
    for (int i = threadIdx.x; i < 10 * 1024; i += 256) {
        int r = i >> 10, c = i & 1023;
        wlds[r * 1033 + c] = W_out[i];
    }
    __syncthreads();

    int tid = threadIdx.x;
    if (tid >= 250) return;
    int tl = tid / 10, rowr = tid - tl * 10;
    int t = blockIdx.x * 25 + tl;
    if (t >= T_STEPS) return;

    float acc = 0.f;
    if (t > 0) {
        const uint2* wp = raster + (size_t)(t - 1) * NBLK;
        const float* wr = &wlds[rowr * 1033];
        for (int ww = 0; ww < NBLK; ++ww) {
            uint2 v = wp[ww];
            unsigned int bits = (v.x & 0xffffu) | ((v.y & 0xffffu) << 16);
            const float* wb = wr + ww * 32;
            #pragma unroll
            for (int j = 0; j < 32; ++j)
                acc = fmaf((float)((bits >> j) & 1u), wb[j], acc);
        }
    }
    R[t * 10 + rowr] = acc;
}

// ---------------------------------------------------------------- phase 2B
__global__ void k_scan(const float* __restrict__ R,
                       const float* __restrict__ alpha_r,
                       const float* __restrict__ beta_r,
                       float* __restrict__ memr_all)   // [T][10]
{
    int lane = threadIdx.x;
    bool act = lane < 10;
    float a = act ? alpha_r[lane >> 1] : 0.f;
    float b = act ? beta_r[lane >> 1] : 0.f;
    float syn = 0.f, mem = 0.f;
    constexpr int PF = 8;
    float buf[PF];
    #pragma unroll
    for (int i = 0; i < PF; ++i) buf[i] = act ? R[i * 10 + lane] : 0.f;

    for (int tb = 0; tb < T_STEPS; tb += PF) {
        #pragma unroll
        for (int i = 0; i < PF; ++i) {
            int t = tb + i;
            syn = fmaf(a, syn, buf[i]);
            mem = fmaf(b, mem, syn);
            if (act) memr_all[t * 10 + lane] = mem;
            int tn = t + PF;
            buf[i] = (act && tn < T_STEPS) ? R[tn * 10 + lane] : 0.f;
        }
    }
}

// ---------------------------------------------------------------- phase 2C
__global__ void k_mean(const float* __restrict__ memr_all, float* __restrict__ out) {
    int g = blockIdx.x * blockDim.x + threadIdx.x;
    if (g >= T_STEPS * 2) return;
    int t = g >> 1, o = g & 1;
    const float* m = memr_all + t * 10 + o;
    out[g] = 0.2f * (m[0] + m[2] + m[4] + m[6] + m[8]);
}

// ---------------------------------------------------------------- launch
extern "C" void kernel_launch(void* const* d_in, const int* in_sizes, int n_in,
                              void* d_out, int out_size, void* d_ws, size_t ws_size,
                              hipStream_t stream) {
    (void)in_sizes; (void)n_in; (void)out_size; (void)ws_size;
    const float* x       = (const float*)d_in[0];
    const float* W_in    = (const float*)d_in[1];
    const float* V       = (const float*)d_in[2];
    const float* b_rec   = (const float*)d_in[3];
    const float* W_out   = (const float*)d_in[4];
    const float* alpha_h = (const float*)d_in[5];
    const float* beta_h  = (const float*)d_in[6];
    const float* alpha_r = (const float*)d_in[7];
    const float* beta_r  = (const float*)d_in[8];
    float* out = (float*)d_out;

    char* wsb = (char*)d_ws;
    unsigned long long* mbox = (unsigned long long*)wsb;   // 4*32*32*8 = 32 KB
    uint2* raster  = (uint2*)(wsb + RING * NBLK * NBLK * 8);          // 2 MB
    float* Rbuf    = (float*)(wsb + RING * NBLK * NBLK * 8
                              + (size_t)T_STEPS * NBLK * 8);          // 320 KB
    float* memr_all = Rbuf + (size_t)T_STEPS * 10;                    // 320 KB

    int nclr = RING * NBLK * NBLK * 2;   // mailbox region in u32s
    k_clear<<<(nclr + 255) / 256, 256, 0, stream>>>((unsigned int*)mbox, nclr);
    k_phase1<<<NBLK, 576, 0, stream>>>(x, W_in, V, b_rec, alpha_h, beta_h,
                                       mbox, raster);
    k_readout_mm<<<(T_STEPS + 24) / 25, 256, 0, stream>>>(raster, W_out, Rbuf);
    k_scan<<<1, 64, 0, stream>>>(Rbuf, alpha_r, beta_r, memr_all);
    k_mean<<<(T_STEPS * 2 + 255) / 256, 256, 0, stream>>>(memr_all, out);
}